// Round 11
// baseline (573.954 us; speedup 1.0000x reference)
//
#include <hip/hip_runtime.h>
#include <stdint.h>

#define NROWS 8192
#define DIM   2048
#define MARGIN 2.0f
#define SCALEQ (127.0f / 6.0f)          // quantize scale
#define S2     ((6.0f / 127.0f) * (6.0f / 127.0f))   // dequant^2

// ---- 256x256 i8 tile kernel geometry (byte units) ----
#define BT2     256
#define BKB     128                      // K-bytes (=elems) per tile-step
#define NKT     (DIM / BKB)              // 16 K-tiles
#define NT2     (NROWS / BT2)            // 32 tile-rows
#define NTILES2 (NT2 * (NT2 + 1) / 2)    // 528 upper-tri tiles
#define NQ      16                       // tiles 0..15 split into 4 row-quarters
// LDS layout (bytes): A-buf0 [0,32K) | A-buf1 [32K,64K) | B-buf0 [64K,96K) | B-buf1 [96K,128K)
#define BREG    65536

typedef __attribute__((ext_vector_type(4)))  int  int4v;    // 16B operand
typedef __attribute__((ext_vector_type(16))) int  int16v;   // 32x32 i32 acc
typedef unsigned char uchar;

// triangular decode (ti <= tj)
__device__ __forceinline__ void decode_tile(int bid, int* ti, int* tj) {
    float fn = (float)NT2 + 0.5f;
    int r = (int)(fn - sqrtf(fn * fn - 2.0f * (float)bid));
    if (r < 0) r = 0;
    if (r >= NT2) r = NT2 - 1;
    while ((r + 1) * NT2 - ((r + 1) * r) / 2 <= bid) ++r;
    while (r * NT2 - (r * (r - 1)) / 2 > bid) --r;
    *ti = r;
    *tj = r + (bid - (r * NT2 - (r * (r - 1)) / 2));
}

__device__ __forceinline__ uint pack4(float4 v) {
    int q0 = (int)__builtin_rintf(v.x * SCALEQ);
    int q1 = (int)__builtin_rintf(v.y * SCALEQ);
    int q2 = (int)__builtin_rintf(v.z * SCALEQ);
    int q3 = (int)__builtin_rintf(v.w * SCALEQ);
    q0 = min(max(q0, -127), 127); q1 = min(max(q1, -127), 127);
    q2 = min(max(q2, -127), 127); q3 = min(max(q3, -127), 127);
    return (uint)(q0 & 0xFF) | ((uint)(q1 & 0xFF) << 8) |
           ((uint)(q2 & 0xFF) << 16) | ((uint)(q3 & 0xFF) << 24);
}

// ---------------- kernel 1: fp32 -> i8 quantize + fp32 row sum of squares ---
__global__ __launch_bounds__(256) void prep_kernel(const float* __restrict__ p,
                                                   uchar* __restrict__ pb,
                                                   float* __restrict__ sq) {
    int row = blockIdx.x;
    int t = threadIdx.x;
    const float4* prow = (const float4*)(p + (size_t)row * DIM);
    uint* qrow = (uint*)(pb + (size_t)row * DIM);
    float4 a = prow[t];
    float4 b = prow[t + 256];
    float s = a.x * a.x + a.y * a.y + a.z * a.z + a.w * a.w
            + b.x * b.x + b.y * b.y + b.z * b.z + b.w * b.w;
    qrow[t] = pack4(a);
    qrow[t + 256] = pack4(b);
#pragma unroll
    for (int o = 32; o > 0; o >>= 1) s += __shfl_down(s, o, 64);
    __shared__ float wsums[4];
    int lane = t & 63, wvv = t >> 6;
    if (lane == 0) wsums[wvv] = s;
    __syncthreads();
    if (t == 0) sq[row] = wsums[0] + wsums[1] + wsums[2] + wsums[3];
}

// ---------------- staging: global -> LDS, linear dest, pre-swizzled src -----
// WHICH: 0 = A half0, 1 = A half1, 2 = B half0, 3 = B half1; runtime K-tile t.
// t >= NKT clamps to t-2 (parity preserved, dead data, write-window safe).
template<int WHICH>
__device__ __forceinline__ void stage_ht(const uchar* __restrict__ pb, uchar* lds,
                                         int t, int ibase, int jbase, int tid) {
    if (t >= NKT) t -= 2;
    constexpr int h = WHICH & 1;
    constexpr bool isB = (WHICH >= 2);
    const int row0 = (isB ? jbase : ibase) + h * 128;
    const uchar* g0 = pb + (size_t)row0 * DIM + t * BKB;
    uchar* l0 = lds + (isB ? BREG : 0) + (t & 1) * 32768 + h * 16384;
#pragma unroll
    for (int r = 0; r < 2; ++r) {
        int row = r * 64 + (tid >> 3);
        int c8 = (tid & 7) ^ ((tid >> 3) & 7);         // pre-swizzled 16B slot
        const uchar* g = g0 + (size_t)row * DIM + c8 * 16;
        uchar* l = l0 + r * 8192 + (tid >> 6) * 1024;  // wave-uniform (+lane*16 HW)
        __builtin_amdgcn_global_load_lds(
            (const __attribute__((address_space(1))) uint32_t*)g,
            (__attribute__((address_space(3))) uint32_t*)l, 16, 0, 0);
    }
}

// quarter-path stages
__device__ __forceinline__ void stage_qB(const uchar* __restrict__ pb, uchar* lds,
                                         int t, int h, int jbase, int tid) {
    if (t >= NKT) t -= 2;
    const uchar* g0 = pb + (size_t)(jbase + h * 128) * DIM + t * BKB;
    uchar* l0 = lds + BREG + (t & 1) * 32768 + h * 16384;
#pragma unroll
    for (int r = 0; r < 2; ++r) {
        int row = r * 64 + (tid >> 3);
        int c8 = (tid & 7) ^ ((tid >> 3) & 7);
        const uchar* g = g0 + (size_t)row * DIM + c8 * 16;
        uchar* l = l0 + r * 8192 + (tid >> 6) * 1024;
        __builtin_amdgcn_global_load_lds(
            (const __attribute__((address_space(1))) uint32_t*)g,
            (__attribute__((address_space(3))) uint32_t*)l, 16, 0, 0);
    }
}
__device__ __forceinline__ void stage_qA(const uchar* __restrict__ pb, uchar* lds,
                                         int t, int ibase, int tid) {
    if (t >= NKT) t -= 2;
    const uchar* g0 = pb + (size_t)ibase * DIM + t * BKB;
    uchar* l0 = lds + (t & 1) * 32768;
    int row = tid >> 3;                                // 0..63
    int c8 = (tid & 7) ^ ((tid >> 3) & 7);
    const uchar* g = g0 + (size_t)row * DIM + c8 * 16;
    uchar* l = l0 + (tid >> 6) * 1024;
    __builtin_amdgcn_global_load_lds(
        (const __attribute__((address_space(1))) uint32_t*)g,
        (__attribute__((address_space(3))) uint32_t*)l, 16, 0, 0);
}

#define BARF()   do { __builtin_amdgcn_s_barrier(); \
                      asm volatile("" ::: "memory"); } while (0)
#define WAITALL() asm volatile("s_waitcnt vmcnt(0) lgkmcnt(0)" ::: "memory")
#define WAITV8() asm volatile("s_waitcnt vmcnt(8)" ::: "memory")
#define WAITV5() asm volatile("s_waitcnt vmcnt(5)" ::: "memory")
#define PRIO1()  __builtin_amdgcn_s_setprio(1)
#define PRIO0()  __builtin_amdgcn_s_setprio(0)
#define SB0()    __builtin_amdgcn_sched_barrier(0)

// full-tile fragment read: all 24 ds_read_b128 for one K-tile into a set.
// addr = precomputed per-lane base (acomb/bcomb) + compile-time const.
#define RD_FULL(AF, B0, B1, BUFO)                                              \
    _Pragma("unroll") for (int mh = 0; mh < 4; ++mh)                           \
    _Pragma("unroll") for (int s = 0; s < 4; ++s)                              \
        AF[mh][s] = *(const int4v*)&lds[acomb[s] + (mh * 4096 + (BUFO))];      \
    _Pragma("unroll") for (int s = 0; s < 4; ++s)                              \
        B0[s] = *(const int4v*)&lds[bcomb[s] + (BUFO)];                        \
    _Pragma("unroll") for (int s = 0; s < 4; ++s)                              \
        B1[s] = *(const int4v*)&lds[bcomb[s] + (4096 + (BUFO))];

#define MFMA_FULL(AF, B0, B1)                                                  \
    _Pragma("unroll") for (int s = 0; s < 4; ++s)                              \
    _Pragma("unroll") for (int mh = 0; mh < 4; ++mh)                           \
        acc[mh][0] = __builtin_amdgcn_mfma_i32_32x32x32_i8(                    \
            AF[mh][s], B0[s], acc[mh][0], 0, 0, 0);                            \
    _Pragma("unroll") for (int s = 0; s < 4; ++s)                              \
    _Pragma("unroll") for (int mh = 0; mh < 4; ++mh)                           \
        acc[mh][1] = __builtin_amdgcn_mfma_i32_32x32x32_i8(                    \
            AF[mh][s], B1[s], acc[mh][1], 0, 0, 0);

// Pipelined step, ONE barrier. At entry: frags(T) in CUR set; buf(T&1) free
// for staging; tile T+1 resident in buf((T+1)&1) (drained last step).
//   stage(T+2)->buf(T&1) | read(T+1)->ALT set | MFMA(T) on CUR | waits | bar
#define STEPP(T, CAF, CB0, CB1, NAF, NB0, NB1, NBUFO)                          \
    {                                                                          \
        stage_ht<2>(pb, lds, (T) + 2, ibase, jbase, tid);                      \
        stage_ht<3>(pb, lds, (T) + 2, ibase, jbase, tid);                      \
        stage_ht<0>(pb, lds, (T) + 2, ibase, jbase, tid);                      \
        stage_ht<1>(pb, lds, (T) + 2, ibase, jbase, tid);                      \
        SB0();                                                                 \
        RD_FULL(NAF, NB0, NB1, NBUFO);                                         \
        SB0();                                                                 \
        PRIO1(); MFMA_FULL(CAF, CB0, CB1); PRIO0();                            \
        WAITALL();                                                             \
        BARF();                                                                \
    }

#define RD_Q(AQ, BQ, BUFO)                                                     \
    _Pragma("unroll") for (int mt = 0; mt < 2; ++mt)                           \
    _Pragma("unroll") for (int s = 0; s < 4; ++s)                              \
        AQ[mt][s] = *(const int4v*)&lds[aqc[s] + (mt * 4096 + (BUFO))];        \
    _Pragma("unroll") for (int s = 0; s < 4; ++s)                              \
        BQ[s] = *(const int4v*)&lds[bqc[s] + (BUFO)];

#define STEP_QP(T, CA, CB, NA, NB, NBUFO)                                      \
    {                                                                          \
        stage_qA(pb, lds, (T) + 2, ibase, tid);                                \
        stage_qB(pb, lds, (T) + 2, 0, jbase, tid);                             \
        stage_qB(pb, lds, (T) + 2, 1, jbase, tid);                             \
        SB0();                                                                 \
        RD_Q(NA, NB, NBUFO);                                                   \
        SB0();                                                                 \
        PRIO1();                                                               \
        _Pragma("unroll") for (int s = 0; s < 4; ++s)                          \
        _Pragma("unroll") for (int mt = 0; mt < 2; ++mt)                       \
            accq[mt] = __builtin_amdgcn_mfma_i32_32x32x32_i8(                  \
                CA[mt][s], CB[s], accq[mt], 0, 0, 0);                          \
        PRIO0();                                                               \
        WAITALL();                                                             \
        BARF();                                                                \
    }

// ---------------- kernel 2: triangular Gram + fused loss --------------------
// Grid = 64 quarter blocks (tiles 0..15 x 4 row-quarters, first) + 512 fulls.
// 512 threads, 8 waves (2 waves/SIMD).
__global__ __launch_bounds__(512) void tile2_kernel(
    const uchar* __restrict__ pb, const float* __restrict__ sq,
    const int* __restrict__ gt, double* __restrict__ accum) {

    __shared__ uchar lds[131072];   // 128 KiB (layout per #define BREG)
    __shared__ float wsum[8];

    const int bx = (int)blockIdx.x;
    const bool is_q = (bx < 4 * NQ);
    int bid, qq = 0;
    if (is_q) { bid = bx >> 2; qq = bx & 3; }
    else { int f = bx - 4 * NQ; bid = NQ + ((f & 7) << 6) + (f >> 3); } // 512=8*64

    int ti, tj;
    decode_tile(bid, &ti, &tj);

    const int tid = threadIdx.x;
    const int lane = tid & 63;
    const int kh = lane >> 5;            // K-half within a 32-wide slice
    const int wv = tid >> 6;             // wave 0..7
    const int wr = wv >> 2;              // full: row half (128 rows)
    const int wc = wv & 3;               // full: col group (64 cols)
    const int jbase = tj * BT2;
    const int ibase = ti * BT2 + (is_q ? qq * 64 : 0);

    const float invd = 1.0f / (float)DIM;
    float lsum = 0.f;

    if (!is_q) {
        int16v acc[4][2] = {};                 // 128 regs -> AGPR file
        int4v afX[4][4], b0X[4], b1X[4];       // frag set X (96 VGPR)
        int4v afY[4][4], b0Y[4], b1Y[4];       // frag set Y (96 VGPR)

        int acomb[4], bcomb[4];
#pragma unroll
        for (int s = 0; s < 4; ++s) {
            int slot = ((2 * s + kh) ^ (lane & 7)) * 16;
            acomb[s] = (wr * 128 + (lane & 31)) * 128 + slot;
            bcomb[s] = BREG + (wc * 64 + (lane & 31)) * 128 + slot;
        }

        // prologue: stage tiles 0,1 (16 vmem); tile0 resident at vmcnt(8);
        // read frags(0) into X; drain everything; barrier.
        stage_ht<2>(pb, lds, 0, ibase, jbase, tid);
        stage_ht<3>(pb, lds, 0, ibase, jbase, tid);
        stage_ht<0>(pb, lds, 0, ibase, jbase, tid);
        stage_ht<1>(pb, lds, 0, ibase, jbase, tid);
        stage_ht<2>(pb, lds, 1, ibase, jbase, tid);
        stage_ht<3>(pb, lds, 1, ibase, jbase, tid);
        stage_ht<0>(pb, lds, 1, ibase, jbase, tid);
        stage_ht<1>(pb, lds, 1, ibase, jbase, tid);
        WAITV8();
        RD_FULL(afX, b0X, b1X, 0);
        WAITALL();
        BARF();

#pragma unroll 1
        for (int s0 = 0; s0 < NKT; s0 += 2) {
            STEPP(s0,     afX, b0X, b1X, afY, b0Y, b1Y, 32768);
            STEPP(s0 + 1, afY, b0Y, b1Y, afX, b0X, b1X, 0);
        }

        // fused epilogue: dequant -> d2 -> contrastive term -> weighted sum
        int j0 = jbase + wc * 64 + (lane & 31);
        float sqj[2]; int gj[2];
#pragma unroll
        for (int n = 0; n < 2; ++n) { int j = j0 + n * 32; sqj[n] = sq[j]; gj[n] = gt[j]; }
        const float wb = (ti != tj) ? 2.0f : 1.0f;
#pragma unroll
        for (int mi = 0; mi < 4; ++mi) {
#pragma unroll
            for (int q = 0; q < 4; ++q) {
#pragma unroll
                for (int rr = 0; rr < 4; ++rr) {
                    int i = ibase + wr * 128 + mi * 32 + rr + 8 * q + 4 * kh;
                    float sqi = sq[i];
                    int gi = gt[i];
#pragma unroll
                    for (int n = 0; n < 2; ++n) {
                        int j = j0 + n * 32;
                        float dot = S2 * (float)acc[mi][n][q * 4 + rr];
                        float d2 = fmaxf(sqi + sqj[n] - 2.0f * dot, 0.0f) * invd;
                        float term = (gi == gj[n]) ? d2 : fmaxf(MARGIN - d2, 0.0f);
                        float w = wb;
                        if (ti == tj && i == j) w = 2.0f;
                        lsum += w * term;
                    }
                }
            }
        }
    } else {
        int16v accq[2] = {};
        int4v aqX[2][4], bqX[4];
        int4v aqY[2][4], bqY[4];

        int aqc[4], bqc[4];
#pragma unroll
        for (int s = 0; s < 4; ++s) {
            int slot = ((2 * s + kh) ^ (lane & 7)) * 16;
            aqc[s] = (lane & 31) * 128 + slot;                       // A rows 0..63
            bqc[s] = BREG + (wv * 32 + (lane & 31)) * 128 + slot;    // B strip
        }

        stage_qA(pb, lds, 0, ibase, tid);
        stage_qB(pb, lds, 0, 0, jbase, tid);
        stage_qB(pb, lds, 0, 1, jbase, tid);
        stage_qA(pb, lds, 1, ibase, tid);
        stage_qB(pb, lds, 1, 0, jbase, tid);
        stage_qB(pb, lds, 1, 1, jbase, tid);
        WAITV5();
        RD_Q(aqX, bqX, 0);
        WAITALL();
        BARF();

#pragma unroll 1
        for (int s0 = 0; s0 < NKT; s0 += 2) {
            STEP_QP(s0,     aqX, bqX, aqY, bqY, 32768);
            STEP_QP(s0 + 1, aqY, bqY, aqX, bqX, 0);
        }

        int j = jbase + wv * 32 + (lane & 31);
        float sqj = sq[j];
        int gj = gt[j];
        const float wb = (ti != tj) ? 2.0f : 1.0f;
#pragma unroll
        for (int mt = 0; mt < 2; ++mt) {
#pragma unroll
            for (int q = 0; q < 4; ++q) {
#pragma unroll
                for (int rr = 0; rr < 4; ++rr) {
                    int i = ibase + mt * 32 + rr + 8 * q + 4 * kh;
                    float dot = S2 * (float)accq[mt][q * 4 + rr];
                    float d2 = fmaxf(sq[i] + sqj - 2.0f * dot, 0.0f) * invd;
                    float term = (gt[i] == gj) ? d2 : fmaxf(MARGIN - d2, 0.0f);
                    float w = wb;
                    if (ti == tj && i == j) w = 2.0f;
                    lsum += w * term;
                }
            }
        }
    }

#pragma unroll
    for (int o = 32; o > 0; o >>= 1) lsum += __shfl_down(lsum, o, 64);
    if (lane == 0) wsum[wv] = lsum;
    __syncthreads();
    if (tid == 0) {
        float s = 0.f;
#pragma unroll
        for (int w = 0; w < 8; ++w) s += wsum[w];
        atomicAdd(accum, (double)s);
    }
}

// ---------------- kernel 3: finalize ----------------------------------------
__global__ void finalize_kernel(const double* __restrict__ accum,
                                float* __restrict__ out) {
    if (threadIdx.x == 0)
        out[0] = (float)(accum[0] * (1.0 / ((double)NROWS * (double)(NROWS - 1))));
}

extern "C" void kernel_launch(void* const* d_in, const int* in_sizes, int n_in,
                              void* d_out, int out_size, void* d_ws, size_t ws_size,
                              hipStream_t stream) {
    (void)in_sizes; (void)n_in; (void)out_size; (void)ws_size;
    const float* p = (const float*)d_in[0];
    const int* gt = (const int*)d_in[1];
    float* out = (float*)d_out;

    // ws layout: pb 16MB i8 | sq 32KB | accum 8B
    uchar* pb = (uchar*)d_ws;
    size_t off = (size_t)NROWS * DIM;                   // 16,777,216
    float* sq = (float*)((char*)d_ws + off);
    off += (size_t)NROWS * sizeof(float);               // +32 KB
    double* accum = (double*)((char*)d_ws + off);

    (void)hipMemsetAsync(accum, 0, sizeof(double), stream);
    prep_kernel<<<NROWS, 256, 0, stream>>>(p, pb, sq);
    tile2_kernel<<<4 * NQ + 512, 512, 0, stream>>>(pb, sq, gt, accum);
    finalize_kernel<<<1, 64, 0, stream>>>(accum, out);
}

// Round 12
// 114.258 us; speedup vs baseline: 5.0233x; 5.0233x over previous
//
#include <hip/hip_runtime.h>
#include <stdint.h>

#define NROWS 8192
#define DIM   2048
#define MARGIN 2.0f
#define SCALEQ (127.0f / 6.0f)          // quantize scale
#define S2     ((6.0f / 127.0f) * (6.0f / 127.0f))   // dequant^2

// ---- 256x256 i8 tile kernel geometry (byte units) ----
#define BT2     256
#define BKB     128                      // K-bytes (=elems) per tile-step
#define NKT     (DIM / BKB)              // 16 K-tiles
#define NT2     (NROWS / BT2)            // 32 tile-rows
#define NTILES2 (NT2 * (NT2 + 1) / 2)    // 528 upper-tri tiles
#define NQ      16                       // tiles 0..15 split into 4 row-quarters
#define ABUF_B  32768                    // A region bytes per buffer (256x128)
#define BUF_B   65536                    // A + B regions per buffer
#define HALF_B  16384                    // 128x128 half-tile bytes

typedef __attribute__((ext_vector_type(4)))  int  int4v;    // 16B operand
typedef __attribute__((ext_vector_type(16))) int  int16v;   // 32x32 i32 acc
typedef unsigned char uchar;

// triangular decode (ti <= tj)
__device__ __forceinline__ void decode_tile(int bid, int* ti, int* tj) {
    float fn = (float)NT2 + 0.5f;
    int r = (int)(fn - sqrtf(fn * fn - 2.0f * (float)bid));
    if (r < 0) r = 0;
    if (r >= NT2) r = NT2 - 1;
    while ((r + 1) * NT2 - ((r + 1) * r) / 2 <= bid) ++r;
    while (r * NT2 - (r * (r - 1)) / 2 > bid) --r;
    *ti = r;
    *tj = r + (bid - (r * NT2 - (r * (r - 1)) / 2));
}

__device__ __forceinline__ uint pack4(float4 v) {
    int q0 = (int)__builtin_rintf(v.x * SCALEQ);
    int q1 = (int)__builtin_rintf(v.y * SCALEQ);
    int q2 = (int)__builtin_rintf(v.z * SCALEQ);
    int q3 = (int)__builtin_rintf(v.w * SCALEQ);
    q0 = min(max(q0, -127), 127); q1 = min(max(q1, -127), 127);
    q2 = min(max(q2, -127), 127); q3 = min(max(q3, -127), 127);
    return (uint)(q0 & 0xFF) | ((uint)(q1 & 0xFF) << 8) |
           ((uint)(q2 & 0xFF) << 16) | ((uint)(q3 & 0xFF) << 24);
}

// ---------------- kernel 1: fp32 -> i8 quantize + fp32 row sum of squares ---
// sq from the fp32 ORIGINALS: cancels the quantization distance-inflation bias.
__global__ __launch_bounds__(256) void prep_kernel(const float* __restrict__ p,
                                                   uchar* __restrict__ pb,
                                                   float* __restrict__ sq) {
    int row = blockIdx.x;
    int t = threadIdx.x;
    const float4* prow = (const float4*)(p + (size_t)row * DIM);
    uint* qrow = (uint*)(pb + (size_t)row * DIM);
    float4 a = prow[t];
    float4 b = prow[t + 256];
    float s = a.x * a.x + a.y * a.y + a.z * a.z + a.w * a.w
            + b.x * b.x + b.y * b.y + b.z * b.z + b.w * b.w;
    qrow[t] = pack4(a);
    qrow[t + 256] = pack4(b);
#pragma unroll
    for (int o = 32; o > 0; o >>= 1) s += __shfl_down(s, o, 64);
    __shared__ float wsums[4];
    int lane = t & 63, wvv = t >> 6;
    if (lane == 0) wsums[wvv] = s;
    __syncthreads();
    if (t == 0) sq[row] = wsums[0] + wsums[1] + wsums[2] + wsums[3];
}

// ---------------- staging: global -> LDS, linear dest, pre-swizzled src -----
// 512 threads, half-tile = 128 rows x 128B = 16KB -> 2 insts/thread.
// which: 0 = A half0, 1 = A half1, 2 = B half0, 3 = B half1, for K-tile t.
// t >= NKT clamps to t-2 (parity preserved, dead data, same write window).
__device__ __forceinline__ void stage_ht(const uchar* __restrict__ pb,
                                         uchar* lds, int t, int which,
                                         int ibase, int jbase, int tid) {
    if (t >= NKT) t -= 2;
    const int h = which & 1;
    const int row0 = ((which >= 2) ? jbase : ibase) + h * 128;
    const uchar* g0 = pb + (size_t)row0 * DIM + t * BKB;
    uchar* l0 = lds + (t & 1) * BUF_B + ((which >= 2) ? ABUF_B : 0) + h * HALF_B;
#pragma unroll
    for (int r = 0; r < 2; ++r) {
        int row = r * 64 + (tid >> 3);
        int c8 = (tid & 7) ^ ((tid >> 3) & 7);         // pre-swizzled 16B slot
        const uchar* g = g0 + (size_t)row * DIM + c8 * 16;
        uchar* l = l0 + r * 8192 + (tid >> 6) * 1024;  // wave-uniform (+lane*16 HW)
        __builtin_amdgcn_global_load_lds(
            (const __attribute__((address_space(1))) uint32_t*)g,
            (__attribute__((address_space(3))) uint32_t*)l, 16, 0, 0);
    }
}

// quarter-block A stage: 64 rows x 128B = 8KB -> 1 inst/thread (512 threads)
__device__ __forceinline__ void stage_qA(const uchar* __restrict__ pb,
                                         uchar* lds, int t, int ibase, int tid) {
    if (t >= NKT) t -= 2;
    const uchar* g0 = pb + (size_t)ibase * DIM + t * BKB;
    uchar* l0 = lds + (t & 1) * BUF_B;
    int row = tid >> 3;                                // 0..63
    int c8 = (tid & 7) ^ ((tid >> 3) & 7);
    const uchar* g = g0 + (size_t)row * DIM + c8 * 16;
    uchar* l = l0 + (tid >> 6) * 1024;
    __builtin_amdgcn_global_load_lds(
        (const __attribute__((address_space(1))) uint32_t*)g,
        (__attribute__((address_space(3))) uint32_t*)l, 16, 0, 0);
}

#define BARF()   do { __builtin_amdgcn_s_barrier(); \
                      asm volatile("" ::: "memory"); } while (0)
#define WAITL()  asm volatile("s_waitcnt lgkmcnt(0)" ::: "memory")
#define WAITV8() asm volatile("s_waitcnt vmcnt(8)" ::: "memory")
#define WAITV5() asm volatile("s_waitcnt vmcnt(5)" ::: "memory")
#define WAITV0() asm volatile("s_waitcnt vmcnt(0)" ::: "memory")
#define PRIO1()  __builtin_amdgcn_s_setprio(1)
#define PRIO0()  __builtin_amdgcn_s_setprio(0)

// swizzled ds_read of 16B i8 frags: row stride 128B, slot ^= (row&7) = (lane&7)
#define READ_A(AB, MH)                                                         \
    _Pragma("unroll") for (int mt = 0; mt < 2; ++mt)                           \
    _Pragma("unroll") for (int s = 0; s < 4; ++s) {                            \
        int rl = wr * 128 + ((MH) * 2 + mt) * 32 + (lane & 31);                \
        af[mt][s] = *(const int4v*)&(AB)[rl * 128 +                            \
                     (((2 * s + kh) ^ (lane & 7)) * 16)];                      \
    }

#define READ_B(BB, NH)                                                         \
    _Pragma("unroll") for (int s = 0; s < 4; ++s) {                            \
        int rl = wc * 64 + (NH) * 32 + (lane & 31);                            \
        bf[NH][s] = *(const int4v*)&(BB)[rl * 128 +                            \
                     (((2 * s + kh) ^ (lane & 7)) * 16)];                      \
    }

#define MFMA_Q(MH, NH)                                                         \
    _Pragma("unroll") for (int mt = 0; mt < 2; ++mt)                           \
    _Pragma("unroll") for (int s = 0; s < 4; ++s)                              \
        acc[(MH) * 2 + mt][NH] = __builtin_amdgcn_mfma_i32_32x32x32_i8(        \
            af[mt][s], bf[NH][s], acc[(MH) * 2 + mt][NH], 0, 0, 0);

// FULL step — ROUND-6 VERBATIM (best measured per-tile: 38.7 us).
// One K-tile = 4 phases. All stages for tile T+2 issue in P3/P4:
//   P3: B0,B1(T+2)->buf (safe: ALL B reads of buf close at end-P2 barrier)
//   P4: A0,A1(T+2)->buf (safe: ALL A reads of buf close at end-P3 barrier)
// Boundary s_waitcnt vmcnt(8): tile T+1's 8 loads retired, T+2's 8 in flight.
#define STEP_FULL(T, BUF)                                                      \
    {                                                                          \
        const uchar* Ab = &lds[(BUF) * BUF_B];                                 \
        const uchar* Bb = &lds[(BUF) * BUF_B + ABUF_B];                        \
        /* P1: Q(0,0) — 12 ds_reads, no stage */                               \
        READ_A(Ab, 0);                                                         \
        READ_B(Bb, 0);                                                         \
        BARF(); WAITL();                                                       \
        PRIO1(); MFMA_Q(0, 0); PRIO0();                                        \
        BARF();                                                                \
        /* P2: Q(0,1) — 4 ds_reads */                                          \
        READ_B(Bb, 1);                                                         \
        BARF(); WAITL();                                                       \
        PRIO1(); MFMA_Q(0, 1); PRIO0();                                        \
        BARF();                                                                \
        /* P3: Q(1,0) — 8 ds_reads + stage B(T+2) */                           \
        READ_A(Ab, 1);                                                         \
        stage_ht(pb, lds, (T) + 2, 2, ibase, jbase, tid);                      \
        stage_ht(pb, lds, (T) + 2, 3, ibase, jbase, tid);                      \
        BARF(); WAITL();                                                       \
        PRIO1(); MFMA_Q(1, 0); PRIO0();                                        \
        BARF();                                                                \
        /* P4: Q(1,1) — stage A(T+2), counted vmcnt at tile boundary */        \
        stage_ht(pb, lds, (T) + 2, 0, ibase, jbase, tid);                      \
        stage_ht(pb, lds, (T) + 2, 1, ibase, jbase, tid);                      \
        PRIO1(); MFMA_Q(1, 1); PRIO0();                                        \
        WAITV8(); BARF();                                                      \
    }

// QUARTER step (64x256 strip; wave w owns cols w*32..w*32+31) — R9 proven.
// Reads drain at WAITL before the barrier, so post-barrier stages into the
// same buffer (incl. tail-clamped dead writes) are race-free.
#define STEP_Q(T, BUF)                                                         \
    {                                                                          \
        const uchar* Ab = &lds[(BUF) * BUF_B];                                 \
        const uchar* Bb = &lds[(BUF) * BUF_B + ABUF_B];                        \
        _Pragma("unroll") for (int mt = 0; mt < 2; ++mt)                       \
        _Pragma("unroll") for (int s = 0; s < 4; ++s) {                        \
            int rl = mt * 32 + (lane & 31);                                    \
            aq[mt][s] = *(const int4v*)&Ab[rl * 128 +                          \
                         (((2 * s + kh) ^ (lane & 7)) * 16)];                  \
        }                                                                      \
        _Pragma("unroll") for (int s = 0; s < 4; ++s) {                        \
            int rl = wv * 32 + (lane & 31);                                    \
            bq[s] = *(const int4v*)&Bb[rl * 128 +                              \
                     (((2 * s + kh) ^ (lane & 7)) * 16)];                      \
        }                                                                      \
        WAITL();                                                               \
        PRIO1();                                                               \
        _Pragma("unroll") for (int s = 0; s < 4; ++s)                          \
        _Pragma("unroll") for (int mt = 0; mt < 2; ++mt)                       \
            accq[mt] = __builtin_amdgcn_mfma_i32_32x32x32_i8(                  \
                aq[mt][s], bq[s], accq[mt], 0, 0, 0);                          \
        PRIO0();                                                               \
        BARF();                                                                \
        stage_qA(pb, lds, (T) + 2, ibase, tid);                                \
        stage_ht(pb, lds, (T) + 2, 2, ibase, jbase, tid);                      \
        stage_ht(pb, lds, (T) + 2, 3, ibase, jbase, tid);                      \
        WAITV5(); BARF();                                                      \
    }

// ---------------- kernel 2: triangular Gram + fused loss --------------------
// Grid = 64 quarter blocks (tiles 0..15 x 4 row-quarters, dispatched first)
//      + 512 full tiles. 512 threads, 8 waves.
__global__ __launch_bounds__(512) void tile2_kernel(
    const uchar* __restrict__ pb, const float* __restrict__ sq,
    const int* __restrict__ gt, double* __restrict__ accum) {

    __shared__ uchar lds[2 * BUF_B];   // 128 KiB
    __shared__ float wsum[8];

    const int bx = (int)blockIdx.x;
    const bool is_q = (bx < 4 * NQ);
    int bid, qq = 0;
    if (is_q) { bid = bx >> 2; qq = bx & 3; }
    else { int f = bx - 4 * NQ; bid = NQ + ((f & 7) << 6) + (f >> 3); } // 512=8*64

    int ti, tj;
    decode_tile(bid, &ti, &tj);

    const int tid = threadIdx.x;
    const int lane = tid & 63;
    const int kh = lane >> 5;            // K-half within a 32-wide slice
    const int wv = tid >> 6;             // wave 0..7
    const int wr = wv >> 2;              // full: row half (128 rows)
    const int wc = wv & 3;               // full: col group (64 cols)
    const int jbase = tj * BT2;
    const int ibase = ti * BT2 + (is_q ? qq * 64 : 0);

    const float invd = 1.0f / (float)DIM;
    float lsum = 0.f;

    if (!is_q) {
        int16v acc[4][2] = {};
        int4v af[2][4];
        int4v bf[2][4];

        // prologue: tiles 0,1 fully issued (16 insts); vmcnt(8) -> tile0 resident.
        stage_ht(pb, lds, 0, 2, ibase, jbase, tid);
        stage_ht(pb, lds, 0, 3, ibase, jbase, tid);
        stage_ht(pb, lds, 0, 0, ibase, jbase, tid);
        stage_ht(pb, lds, 0, 1, ibase, jbase, tid);
        stage_ht(pb, lds, 1, 2, ibase, jbase, tid);
        stage_ht(pb, lds, 1, 3, ibase, jbase, tid);
        stage_ht(pb, lds, 1, 0, ibase, jbase, tid);
        stage_ht(pb, lds, 1, 1, ibase, jbase, tid);
        WAITV8();
        BARF();

#pragma unroll 1
        for (int s0 = 0; s0 < NKT; s0 += 2) {
            STEP_FULL(s0, 0);
            STEP_FULL(s0 + 1, 1);
        }
        WAITV0();
        BARF();

        // fused epilogue: dequant -> d2 -> contrastive term -> weighted sum
        int j0 = jbase + wc * 64 + (lane & 31);
        float sqj[2]; int gj[2];
#pragma unroll
        for (int n = 0; n < 2; ++n) { int j = j0 + n * 32; sqj[n] = sq[j]; gj[n] = gt[j]; }
        const float wb = (ti != tj) ? 2.0f : 1.0f;
#pragma unroll
        for (int mi = 0; mi < 4; ++mi) {
#pragma unroll
            for (int q = 0; q < 4; ++q) {
#pragma unroll
                for (int rr = 0; rr < 4; ++rr) {
                    int i = ibase + wr * 128 + mi * 32 + rr + 8 * q + 4 * kh;
                    float sqi = sq[i];
                    int gi = gt[i];
#pragma unroll
                    for (int n = 0; n < 2; ++n) {
                        int j = j0 + n * 32;
                        float dot = S2 * (float)acc[mi][n][q * 4 + rr];
                        float d2 = fmaxf(sqi + sqj[n] - 2.0f * dot, 0.0f) * invd;
                        float term = (gi == gj[n]) ? d2 : fmaxf(MARGIN - d2, 0.0f);
                        float w = wb;
                        if (ti == tj && i == j) w = 2.0f;
                        lsum += w * term;
                    }
                }
            }
        }
    } else {
        int16v accq[2] = {};
        int4v aq[2][4], bq[4];

        // prologue: tiles 0,1 (5 insts each); vmcnt(5) -> tile0 resident.
        stage_qA(pb, lds, 0, ibase, tid);
        stage_ht(pb, lds, 0, 2, ibase, jbase, tid);
        stage_ht(pb, lds, 0, 3, ibase, jbase, tid);
        stage_qA(pb, lds, 1, ibase, tid);
        stage_ht(pb, lds, 1, 2, ibase, jbase, tid);
        stage_ht(pb, lds, 1, 3, ibase, jbase, tid);
        WAITV5();
        BARF();

#pragma unroll 1
        for (int s0 = 0; s0 < NKT; s0 += 2) {
            STEP_Q(s0, 0);
            STEP_Q(s0 + 1, 1);
        }
        WAITV0();
        BARF();

        int j = jbase + wv * 32 + (lane & 31);
        float sqj = sq[j];
        int gj = gt[j];
        const float wb = (ti != tj) ? 2.0f : 1.0f;
#pragma unroll
        for (int mt = 0; mt < 2; ++mt) {
#pragma unroll
            for (int q = 0; q < 4; ++q) {
#pragma unroll
                for (int rr = 0; rr < 4; ++rr) {
                    int i = ibase + mt * 32 + rr + 8 * q + 4 * kh;
                    float dot = S2 * (float)accq[mt][q * 4 + rr];
                    float d2 = fmaxf(sq[i] + sqj - 2.0f * dot, 0.0f) * invd;
                    float term = (gt[i] == gj) ? d2 : fmaxf(MARGIN - d2, 0.0f);
                    float w = wb;
                    if (ti == tj && i == j) w = 2.0f;
                    lsum += w * term;
                }
            }
        }
    }

#pragma unroll
    for (int o = 32; o > 0; o >>= 1) lsum += __shfl_down(lsum, o, 64);
    if (lane == 0) wsum[wv] = lsum;
    __syncthreads();
    if (tid == 0) {
        float s = 0.f;
#pragma unroll
        for (int w = 0; w < 8; ++w) s += wsum[w];
        atomicAdd(accum, (double)s);
    }
}

// ---------------- kernel 3: finalize ----------------------------------------
__global__ void finalize_kernel(const double* __restrict__ accum,
                                float* __restrict__ out) {
    if (threadIdx.x == 0)
        out[0] = (float)(accum[0] * (1.0 / ((double)NROWS * (double)(NROWS - 1))));
}

extern "C" void kernel_launch(void* const* d_in, const int* in_sizes, int n_in,
                              void* d_out, int out_size, void* d_ws, size_t ws_size,
                              hipStream_t stream) {
    (void)in_sizes; (void)n_in; (void)out_size; (void)ws_size;
    const float* p = (const float*)d_in[0];
    const int* gt = (const int*)d_in[1];
    float* out = (float*)d_out;

    // ws layout: pb 16MB i8 | sq 32KB | accum 8B
    uchar* pb = (uchar*)d_ws;
    size_t off = (size_t)NROWS * DIM;                   // 16,777,216
    float* sq = (float*)((char*)d_ws + off);
    off += (size_t)NROWS * sizeof(float);               // +32 KB
    double* accum = (double*)((char*)d_ws + off);

    (void)hipMemsetAsync(accum, 0, sizeof(double), stream);
    prep_kernel<<<NROWS, 256, 0, stream>>>(p, pb, sq);
    tile2_kernel<<<4 * NQ + 512, 512, 0, stream>>>(pb, sq, gt, accum);
    finalize_kernel<<<1, 64, 0, stream>>>(accum, out);
}